// Round 1
// 1667.579 us; speedup vs baseline: 3.2835x; 3.2835x over previous
//
#include <hip/hip_runtime.h>
#include <stdint.h>

// ---------------- bf16 helpers -------------------------------------------
__device__ __forceinline__ float bf2f(uint16_t u) {
    uint32_t x = ((uint32_t)u) << 16;
    float f;
    __builtin_memcpy(&f, &x, 4);
    return f;
}
__device__ __forceinline__ uint16_t f2bf(float f) {
    uint32_t u;
    __builtin_memcpy(&u, &f, 4);
    uint32_t r = (u + 0x7fffu + ((u >> 16) & 1u)) >> 16;  // RNE
    return (uint16_t)r;
}
__device__ __forceinline__ float loadf(const float* p) { return *p; }
__device__ __forceinline__ float loadf(const uint16_t* p) { return bf2f(*p); }

typedef __attribute__((ext_vector_type(8))) short short8;   // 8 bf16 (MFMA A/B)
typedef __attribute__((ext_vector_type(4))) float floatx4;  // MFMA C/D

// ---------------- dtype detector ------------------------------------------
__global__ void detect_dtype(const uint16_t* __restrict__ x, int* __restrict__ flag) {
    int lane = threadIdx.x;  // 64 threads
    int cnt = 0;
    for (int i = 0; i < 8; ++i) {
        uint16_t u = x[lane * 8 + i];
        int e = (u >> 7) & 0xff;
        if (u == 0 || (e >= 96 && e <= 159)) ++cnt;
    }
    for (int off = 32; off; off >>= 1) cnt += __shfl_down(cnt, off);
    if (lane == 0) *flag = (cnt >= 448) ? 1 : 0;  // 1 = bf16 inputs, 0 = f32
}

// ---------------- Cayley via Newton-Schulz, all 8 matrices in ONE launch ---
// Per block: one n x n problem entirely in LDS (M, Y, T all resident).
// Compile-time N -> fully unrolled, register-blocked (RB=N/16 per thread in
// each dim, 16x16 thread tiling). 5 NS iterations: residual = ||S^2||^(2^5)
// ~ 0.26^32 ~ 1e-19, converged to fp32 long before that.
struct CayleyJobs {
    const void* W[8];
    float* out[8];
};

template <int N>
__device__ __forceinline__ void cayley_block(const char* __restrict__ Wb, int isb,
                                             float* __restrict__ O,
                                             float* __restrict__ Ms,
                                             float* __restrict__ Ys,
                                             float* __restrict__ Ts) {
    constexpr int ST = N + 1;   // pad leading dim
    constexpr int RB = N / 16;  // 80->5, 48->3, 16->1
    const int tid = threadIdx.x;
    // stage: Ms = I+S, Ys = I-S  (S = W - W^T)
    for (int e = tid; e < N * N; e += 256) {
        int i = e / N, j = e - i * N;
        float wij, wji;
        if (isb) {
            wij = bf2f(((const uint16_t*)Wb)[i * N + j]);
            wji = bf2f(((const uint16_t*)Wb)[j * N + i]);
        } else {
            wij = ((const float*)Wb)[i * N + j];
            wji = ((const float*)Wb)[j * N + i];
        }
        float s = wij - wji;
        float idt = (i == j) ? 1.f : 0.f;
        Ms[i * ST + j] = idt + s;
        Ys[i * ST + j] = idt - s;
    }
    __syncthreads();
    const int i0 = (tid >> 4) * RB, j0 = (tid & 15) * RB;
    float acc[RB][RB];

#define MMUL(Amat, Bmat)                                                          \
    _Pragma("unroll") for (int r = 0; r < RB; ++r)                                \
        _Pragma("unroll") for (int c = 0; c < RB; ++c) acc[r][c] = 0.f;           \
    _Pragma("unroll 4") for (int k = 0; k < N; ++k) {                             \
        float a_[RB], b_[RB];                                                     \
        _Pragma("unroll") for (int r = 0; r < RB; ++r)                            \
            a_[r] = Amat[(i0 + r) * ST + k];                                      \
        _Pragma("unroll") for (int c = 0; c < RB; ++c)                            \
            b_[c] = Bmat[k * ST + j0 + c];                                        \
        _Pragma("unroll") for (int r = 0; r < RB; ++r)                            \
            _Pragma("unroll") for (int c = 0; c < RB; ++c)                        \
                acc[r][c] = fmaf(a_[r], b_[c], acc[r][c]);                        \
    }

    for (int it = 0; it < 5; ++it) {
        // Ts = 2I - Ms*Ys
        MMUL(Ms, Ys);
#pragma unroll
        for (int r = 0; r < RB; ++r)
#pragma unroll
            for (int c = 0; c < RB; ++c)
                Ts[(i0 + r) * ST + j0 + c] =
                    ((i0 + r) == (j0 + c) ? 2.f : 0.f) - acc[r][c];
        __syncthreads();
        // Ynew = Ys*Ts (in regs), write back after all reads complete
        MMUL(Ys, Ts);
        __syncthreads();
#pragma unroll
        for (int r = 0; r < RB; ++r)
#pragma unroll
            for (int c = 0; c < RB; ++c) Ys[(i0 + r) * ST + j0 + c] = acc[r][c];
        __syncthreads();
    }
    // Q = 2Y - Y*M
    MMUL(Ys, Ms);
#pragma unroll
    for (int r = 0; r < RB; ++r)
#pragma unroll
        for (int c = 0; c < RB; ++c)
            O[(i0 + r) * N + j0 + c] =
                2.f * Ys[(i0 + r) * ST + j0 + c] - acc[r][c];
#undef MMUL
}

__global__ __launch_bounds__(256) void cayley_all(CayleyJobs jobs,
                                                  const int* __restrict__ flag) {
    __shared__ float lds[3 * 80 * 81];  // 77,760 B: Ms | Ys | Ts
    const int isb = *flag;
    const int bid = blockIdx.x;
    int j, start, n;
    if (bid < 16)       { j = 0; start = 0;   n = 80; }
    else if (bid < 96)  { j = 1; start = 16;  n = 16; }
    else if (bid < 112) { j = 2; start = 96;  n = 48; }
    else if (bid < 160) { j = 3; start = 112; n = 16; }
    else if (bid < 176) { j = 4; start = 160; n = 48; }
    else if (bid < 224) { j = 5; start = 176; n = 16; }
    else if (bid < 240) { j = 6; start = 224; n = 80; }
    else                { j = 7; start = 240; n = 16; }
    const int sub = bid - start;
    const size_t esz = isb ? 2 : 4;
    const char* Wb = (const char*)jobs.W[j] + (size_t)sub * n * n * esz;
    float* O = jobs.out[j] + (size_t)sub * n * n;
    float* Ms = lds;
    float* Ys = lds + 80 * 81;
    float* Ts = lds + 2 * 80 * 81;
    if (n == 80)
        cayley_block<80>(Wb, isb, O, Ms, Ys, Ts);
    else if (n == 48)
        cayley_block<48>(Wb, isb, O, Ms, Ys, Ts);
    else
        cayley_block<16>(Wb, isb, O, Ms, Ys, Ts);
}

// ------- fused fold: WeffT[o][k*bdim+b] = sc[o]*sum_c A[k][b][c]*t[c],
//         t[c] = sum_j B[c][k][j]*W[o][j*bdim+c].  One block per o. ---------
template <typename T>
__global__ __launch_bounds__(256) void build_weff2(const T* __restrict__ W,
                                                   const float* __restrict__ Ac,
                                                   const float* __restrict__ Bc,
                                                   const T* __restrict__ scale,
                                                   uint16_t* __restrict__ WeffT,
                                                   int bdim, int Din,
                                                   const int* __restrict__ flag, int want) {
    if (*flag != want) return;
    __shared__ float Wrow[1280];
    __shared__ float tvec[80];
    const int o = blockIdx.x, tid = threadIdx.x;
    for (int i = tid; i < Din; i += 256) Wrow[i] = loadf(W + (size_t)o * Din + i);
    __syncthreads();
    float sc = loadf(scale + o);
    for (int k = 0; k < 16; ++k) {
        if (tid < bdim) {
            const float* Bm = Bc + tid * 256 + k * 16;  // B[c=tid][k][j]
            float s = 0.f;
#pragma unroll
            for (int j = 0; j < 16; ++j) s += Bm[j] * Wrow[j * bdim + tid];
            tvec[tid] = s;
        }
        __syncthreads();
        if (tid < bdim) {  // tid = beta
            const float* Am = Ac + ((size_t)k * bdim + tid) * bdim;
            float s = 0.f;
            for (int c = 0; c < bdim; ++c) s += Am[c] * tvec[c];
            WeffT[(size_t)o * Din + k * bdim + tid] = f2bf(s * sc);
        }
        __syncthreads();
    }
}

// ---------------- C[M][N] = A[M][K]*Bt[N][K]^T (+bias), bf16 MFMA ----------
#define BM 128
#define BN 128
#define BKK 32
template <typename T>
__global__ __launch_bounds__(256) void gemm_bt(const T* __restrict__ A,
                                               const uint16_t* __restrict__ Bt,
                                               void* __restrict__ Cv,
                                               const void* __restrict__ biasv,
                                               int M, int N, int K,
                                               const int* __restrict__ flag, int want,
                                               int flagio) {
    if (want >= 0 && *flag != want) return;
    const bool io32 = flagio && (*flag == 0);
    __shared__ uint16_t As[BM * BKK];
    __shared__ uint16_t Bs[BN * BKK];
    const int n0 = blockIdx.x * BN, m0 = blockIdx.y * BM;
    const int tid = threadIdx.x;
    const int wave = tid >> 6, lane = tid & 63;
    const int wm = (wave & 1) * 64, wn = (wave >> 1) * 64;
    const int l16 = lane & 15, quad = lane >> 4;

    floatx4 acc[4][4];
#pragma unroll
    for (int i = 0; i < 4; ++i)
#pragma unroll
        for (int j = 0; j < 4; ++j) {
            floatx4 z = {0.f, 0.f, 0.f, 0.f};
            acc[i][j] = z;
        }

    for (int k0 = 0; k0 < K; k0 += BKK) {
        // B staging: 512 x 16B chunks
#pragma unroll
        for (int r = 0; r < 2; ++r) {
            int chunk = tid + r * 256;
            int row = chunk >> 2, c4 = chunk & 3;
            *(uint4*)(&Bs[row * BKK + c4 * 8]) =
                *(const uint4*)(Bt + (size_t)(n0 + row) * K + k0 + c4 * 8);
        }
        // A staging
        if constexpr (sizeof(T) == 2) {
#pragma unroll
            for (int r = 0; r < 2; ++r) {
                int chunk = tid + r * 256;
                int row = chunk >> 2, c4 = chunk & 3;
                int ar = m0 + row;
                ar = ar < M ? ar : M - 1;  // ragged M: clamp load, mask store
                *(uint4*)(&As[row * BKK + c4 * 8]) =
                    *(const uint4*)(A + (size_t)ar * K + k0 + c4 * 8);
            }
        } else {
#pragma unroll
            for (int r = 0; r < 4; ++r) {
                int chunk = tid + r * 256;  // 1024 x float4 chunks
                int row = chunk >> 3, c8 = chunk & 7;
                int ar = m0 + row;
                ar = ar < M ? ar : M - 1;
                float4 v = *(const float4*)(A + (size_t)ar * K + k0 + c8 * 4);
                uint32_t p0 = (uint32_t)f2bf(v.x) | ((uint32_t)f2bf(v.y) << 16);
                uint32_t p1 = (uint32_t)f2bf(v.z) | ((uint32_t)f2bf(v.w) << 16);
                *(uint2*)(&As[row * BKK + c8 * 4]) = make_uint2(p0, p1);
            }
        }
        __syncthreads();
        short8 af[4], bfr[4];
#pragma unroll
        for (int i = 0; i < 4; ++i)
            af[i] = *(const short8*)(&As[(wm + i * 16 + l16) * BKK + quad * 8]);
#pragma unroll
        for (int j = 0; j < 4; ++j)
            bfr[j] = *(const short8*)(&Bs[(wn + j * 16 + l16) * BKK + quad * 8]);
#pragma unroll
        for (int i = 0; i < 4; ++i)
#pragma unroll
            for (int j = 0; j < 4; ++j)
                acc[i][j] = __builtin_amdgcn_mfma_f32_16x16x32_bf16(af[i], bfr[j],
                                                                    acc[i][j], 0, 0, 0);
        __syncthreads();
    }

    // C/D layout: col = lane&15, row = quad*4 + reg  [m89/m91-verified]
#pragma unroll
    for (int i = 0; i < 4; ++i) {
#pragma unroll
        for (int r = 0; r < 4; ++r) {
            int row = m0 + wm + i * 16 + quad * 4 + r;
            if (row < M) {
#pragma unroll
                for (int j = 0; j < 4; ++j) {
                    int col = n0 + wn + j * 16 + l16;
                    float v = acc[i][j][r];
                    if (biasv)
                        v += io32 ? ((const float*)biasv)[col]
                                  : bf2f(((const uint16_t*)biasv)[col]);
                    size_t idx = (size_t)row * N + col;
                    if (io32)
                        ((float*)Cv)[idx] = v;
                    else
                        ((uint16_t*)Cv)[idx] = f2bf(v);
                }
            }
        }
    }
}

// ---------------- attention: T=77, dh=64, per-thread q-row -----------------
__global__ __launch_bounds__(256) void attn_fused(const uint16_t* __restrict__ kbuf,
                                                  const uint16_t* __restrict__ vbuf,
                                                  uint16_t* __restrict__ qbuf,
                                                  int B, int S) {
    __shared__ float KT[64 * 80];  // [d][t], t padded 77->80, pads zeroed
    __shared__ float VT[64 * 80];
    const int b = blockIdx.z, h = blockIdx.y;
    const int tid = threadIdx.x;
    for (int e = tid; e < 64 * 80; e += 256) {
        int d = e / 80, t = e - d * 80;
        float kk = 0.f, vv = 0.f;
        if (t < 77) {
            size_t gi = ((size_t)(b * 77 + t)) * 1280 + h * 64 + d;
            kk = bf2f(kbuf[gi]);
            vv = bf2f(vbuf[gi]);
        }
        KT[e] = kk;
        VT[e] = vv;
    }
    __syncthreads();
    const int s = blockIdx.x * 256 + tid;
    uint16_t* qrow = qbuf + ((size_t)b * S + s) * 1280 + h * 64;

    float sc[80];
#pragma unroll
    for (int t = 0; t < 80; ++t) sc[t] = 0.f;

    const uint4* qp = (const uint4*)qrow;
#pragma unroll 1
    for (int c = 0; c < 8; ++c) {
        uint4 qv = qp[c];
        float qf[8];
        qf[0] = bf2f((uint16_t)(qv.x & 0xffff)); qf[1] = bf2f((uint16_t)(qv.x >> 16));
        qf[2] = bf2f((uint16_t)(qv.y & 0xffff)); qf[3] = bf2f((uint16_t)(qv.y >> 16));
        qf[4] = bf2f((uint16_t)(qv.z & 0xffff)); qf[5] = bf2f((uint16_t)(qv.z >> 16));
        qf[6] = bf2f((uint16_t)(qv.w & 0xffff)); qf[7] = bf2f((uint16_t)(qv.w >> 16));
#pragma unroll
        for (int dd = 0; dd < 8; ++dd) {
            const float* Kr = &KT[(c * 8 + dd) * 80];
#pragma unroll
            for (int t4 = 0; t4 < 20; ++t4) {
                float4 k4 = *(const float4*)(Kr + 4 * t4);
                sc[4 * t4 + 0] = fmaf(qf[dd], k4.x, sc[4 * t4 + 0]);
                sc[4 * t4 + 1] = fmaf(qf[dd], k4.y, sc[4 * t4 + 1]);
                sc[4 * t4 + 2] = fmaf(qf[dd], k4.z, sc[4 * t4 + 2]);
                sc[4 * t4 + 3] = fmaf(qf[dd], k4.w, sc[4 * t4 + 3]);
            }
        }
    }

    float mx = -1e30f;
#pragma unroll
    for (int t = 0; t < 77; ++t) {
        sc[t] *= 0.125f;  // dh^-0.5
        mx = fmaxf(mx, sc[t]);
    }
    float den = 0.f;
#pragma unroll
    for (int t = 0; t < 77; ++t) {
        float p = __expf(sc[t] - mx);
        sc[t] = p;
        den += p;
    }
    float rden = 1.f / den;
#pragma unroll
    for (int t = 0; t < 77; ++t) sc[t] *= rden;
    sc[77] = sc[78] = sc[79] = 0.f;

#pragma unroll 1
    for (int c = 0; c < 8; ++c) {
        uint32_t pk[4];
#pragma unroll
        for (int dd = 0; dd < 8; dd += 2) {
            float o0 = 0.f, o1 = 0.f;
            const float* V0 = &VT[(c * 8 + dd) * 80];
            const float* V1 = &VT[(c * 8 + dd + 1) * 80];
#pragma unroll
            for (int t4 = 0; t4 < 20; ++t4) {
                float4 v0 = *(const float4*)(V0 + 4 * t4);
                float4 v1 = *(const float4*)(V1 + 4 * t4);
                o0 = fmaf(sc[4 * t4 + 0], v0.x, o0);
                o0 = fmaf(sc[4 * t4 + 1], v0.y, o0);
                o0 = fmaf(sc[4 * t4 + 2], v0.z, o0);
                o0 = fmaf(sc[4 * t4 + 3], v0.w, o0);
                o1 = fmaf(sc[4 * t4 + 0], v1.x, o1);
                o1 = fmaf(sc[4 * t4 + 1], v1.y, o1);
                o1 = fmaf(sc[4 * t4 + 2], v1.z, o1);
                o1 = fmaf(sc[4 * t4 + 3], v1.w, o1);
            }
            pk[dd >> 1] = (uint32_t)f2bf(o0) | ((uint32_t)f2bf(o1) << 16);
        }
        uint4 ov;
        ov.x = pk[0]; ov.y = pk[1]; ov.z = pk[2]; ov.w = pk[3];
        *(uint4*)(qrow + c * 8) = ov;
    }
}

// ---------------------------------------------------------------------------
extern "C" void kernel_launch(void* const* d_in, const int* in_sizes, int n_in,
                              void* d_out, int out_size, void* d_ws, size_t ws_size,
                              hipStream_t stream) {
    (void)in_sizes; (void)n_in; (void)out_size; (void)ws_size;

    // workspace layout (256B-aligned), total ~94.7 MB
    char* ws = (char*)d_ws;
    int* flag      = (int*)(ws + 0);
    float* AcQ     = (float*)(ws + 409856);
    float* AcK     = (float*)(ws + 819456);
    float* AcV     = (float*)(ws + 966912);
    float* AcO     = (float*)(ws + 1114368);
    float* BcQ     = (float*)(ws + 1523968);
    float* BcK     = (float*)(ws + 1605888);
    float* BcV     = (float*)(ws + 1655040);
    float* BcO     = (float*)(ws + 1704192);
    uint16_t* WqT  = (uint16_t*)(ws + 1786112);   // [1280][1280]
    uint16_t* WkT  = (uint16_t*)(ws + 5062912);   // [1280][768]
    uint16_t* WvT  = (uint16_t*)(ws + 7028992);
    uint16_t* WoT  = (uint16_t*)(ws + 8995072);   // [1280][1280]
    uint16_t* kb   = (uint16_t*)(ws + 12271872);  // [616][1280]
    uint16_t* vb   = (uint16_t*)(ws + 13848832);
    uint16_t* qb   = (uint16_t*)(ws + 15425792);  // [32768][1280]

    detect_dtype<<<1, 64, 0, stream>>>((const uint16_t*)d_in[0], flag);

    // Cayley (Newton-Schulz): all 8 matrices, both dtypes, ONE launch.
    // Blocks: 16(AcQ,80) 80(BcQ,16) 16(AcK,48) 48(BcK,16) 16(AcV,48)
    //         48(BcV,16) 16(AcO,80) 80(BcO,16) = 320
    CayleyJobs cj;
    cj.W[0] = d_in[2]; cj.out[0] = AcQ;
    cj.W[1] = d_in[3]; cj.out[1] = BcQ;
    cj.W[2] = d_in[4]; cj.out[2] = AcK;
    cj.W[3] = d_in[5]; cj.out[3] = BcK;
    cj.W[4] = d_in[6]; cj.out[4] = AcV;
    cj.W[5] = d_in[7]; cj.out[5] = BcV;
    cj.W[6] = d_in[8]; cj.out[6] = AcO;
    cj.W[7] = d_in[9]; cj.out[7] = BcO;
    cayley_all<<<320, 256, 0, stream>>>(cj, flag);

    // Fold Monarch + W^T + scale -> WeffT (bf16), dual-launched
#define WEFF(widx, Ac, Bc, sidx, dst, bdim, Din)                                  \
    build_weff2<uint16_t><<<1280, 256, 0, stream>>>((const uint16_t*)d_in[widx], Ac, Bc, \
        (const uint16_t*)d_in[sidx], dst, bdim, Din, flag, 1);                    \
    build_weff2<float><<<1280, 256, 0, stream>>>((const float*)d_in[widx], Ac, Bc,       \
        (const float*)d_in[sidx], dst, bdim, Din, flag, 0)
    WEFF(10, AcQ, BcQ, 15, WqT, 80, 1280);
    WEFF(11, AcK, BcK, 16, WkT, 48, 768);
    WEFF(12, AcV, BcV, 17, WvT, 48, 768);
    WEFF(13, AcO, BcO, 18, WoT, 80, 1280);
#undef WEFF

    // Projections (C always bf16 internal)
    gemm_bt<uint16_t><<<dim3(10, 256), 256, 0, stream>>>((const uint16_t*)d_in[0], WqT, qb,
                                                         nullptr, 32768, 1280, 1280, flag, 1, 0);
    gemm_bt<float><<<dim3(10, 256), 256, 0, stream>>>((const float*)d_in[0], WqT, qb,
                                                      nullptr, 32768, 1280, 1280, flag, 0, 0);
    gemm_bt<uint16_t><<<dim3(10, 5), 256, 0, stream>>>((const uint16_t*)d_in[1], WkT, kb,
                                                       nullptr, 616, 1280, 768, flag, 1, 0);
    gemm_bt<float><<<dim3(10, 5), 256, 0, stream>>>((const float*)d_in[1], WkT, kb,
                                                    nullptr, 616, 1280, 768, flag, 0, 0);
    gemm_bt<uint16_t><<<dim3(10, 5), 256, 0, stream>>>((const uint16_t*)d_in[1], WvT, vb,
                                                       nullptr, 616, 1280, 768, flag, 1, 0);
    gemm_bt<float><<<dim3(10, 5), 256, 0, stream>>>((const float*)d_in[1], WvT, vb,
                                                    nullptr, 616, 1280, 768, flag, 0, 0);

    // Attention (in-place on qb, always bf16)
    attn_fused<<<dim3(16, 20, 8), 256, 0, stream>>>(kb, vb, qb, 8, 4096);

    // Output projection + bias -> d_out, out dtype follows flag
    gemm_bt<uint16_t><<<dim3(10, 256), 256, 0, stream>>>(qb, WoT, d_out, d_in[14],
                                                         32768, 1280, 1280, flag, -1, 1);
}

// Round 2
// 1107.418 us; speedup vs baseline: 4.9444x; 1.5058x over previous
//
#include <hip/hip_runtime.h>
#include <stdint.h>

// ---------------- bf16 helpers -------------------------------------------
__device__ __forceinline__ float bf2f(uint16_t u) {
    uint32_t x = ((uint32_t)u) << 16;
    float f;
    __builtin_memcpy(&f, &x, 4);
    return f;
}
__device__ __forceinline__ uint16_t f2bf(float f) {
    uint32_t u;
    __builtin_memcpy(&u, &f, 4);
    uint32_t r = (u + 0x7fffu + ((u >> 16) & 1u)) >> 16;  // RNE
    return (uint16_t)r;
}
__device__ __forceinline__ float loadf(const float* p) { return *p; }
__device__ __forceinline__ float loadf(const uint16_t* p) { return bf2f(*p); }

typedef __attribute__((ext_vector_type(8))) short short8;   // 8 bf16 (MFMA A/B)
typedef __attribute__((ext_vector_type(4))) float floatx4;  // MFMA C/D

// ---------------- dtype detector ------------------------------------------
__global__ void detect_dtype(const uint16_t* __restrict__ x, int* __restrict__ flag) {
    int lane = threadIdx.x;  // 64 threads
    int cnt = 0;
    for (int i = 0; i < 8; ++i) {
        uint16_t u = x[lane * 8 + i];
        int e = (u >> 7) & 0xff;
        if (u == 0 || (e >= 96 && e <= 159)) ++cnt;
    }
    for (int off = 32; off; off >>= 1) cnt += __shfl_down(cnt, off);
    if (lane == 0) *flag = (cnt >= 448) ? 1 : 0;  // 1 = bf16 inputs, 0 = f32
}

// ---------------- Cayley via Newton-Schulz, all 8 matrices in ONE launch ---
struct CayleyJobs {
    const void* W[8];
    float* out[8];
};

template <int N>
__device__ __forceinline__ void cayley_block(const char* __restrict__ Wb, int isb,
                                             float* __restrict__ O,
                                             float* __restrict__ Ms,
                                             float* __restrict__ Ys,
                                             float* __restrict__ Ts) {
    constexpr int ST = N + 1;   // pad leading dim
    constexpr int RB = N / 16;  // 80->5, 48->3, 16->1
    const int tid = threadIdx.x;
    // stage: Ms = I+S, Ys = I-S  (S = W - W^T)
    for (int e = tid; e < N * N; e += 256) {
        int i = e / N, j = e - i * N;
        float wij, wji;
        if (isb) {
            wij = bf2f(((const uint16_t*)Wb)[i * N + j]);
            wji = bf2f(((const uint16_t*)Wb)[j * N + i]);
        } else {
            wij = ((const float*)Wb)[i * N + j];
            wji = ((const float*)Wb)[j * N + i];
        }
        float s = wij - wji;
        float idt = (i == j) ? 1.f : 0.f;
        Ms[i * ST + j] = idt + s;
        Ys[i * ST + j] = idt - s;
    }
    __syncthreads();
    const int i0 = (tid >> 4) * RB, j0 = (tid & 15) * RB;
    float acc[RB][RB];

#define MMUL(Amat, Bmat)                                                          \
    _Pragma("unroll") for (int r = 0; r < RB; ++r)                                \
        _Pragma("unroll") for (int c = 0; c < RB; ++c) acc[r][c] = 0.f;           \
    _Pragma("unroll 4") for (int k = 0; k < N; ++k) {                             \
        float a_[RB], b_[RB];                                                     \
        _Pragma("unroll") for (int r = 0; r < RB; ++r)                            \
            a_[r] = Amat[(i0 + r) * ST + k];                                      \
        _Pragma("unroll") for (int c = 0; c < RB; ++c)                            \
            b_[c] = Bmat[k * ST + j0 + c];                                        \
        _Pragma("unroll") for (int r = 0; r < RB; ++r)                            \
            _Pragma("unroll") for (int c = 0; c < RB; ++c)                        \
                acc[r][c] = fmaf(a_[r], b_[c], acc[r][c]);                        \
    }

    for (int it = 0; it < 5; ++it) {
        // Ts = 2I - Ms*Ys
        MMUL(Ms, Ys);
#pragma unroll
        for (int r = 0; r < RB; ++r)
#pragma unroll
            for (int c = 0; c < RB; ++c)
                Ts[(i0 + r) * ST + j0 + c] =
                    ((i0 + r) == (j0 + c) ? 2.f : 0.f) - acc[r][c];
        __syncthreads();
        // Ynew = Ys*Ts (in regs), write back after all reads complete
        MMUL(Ys, Ts);
        __syncthreads();
#pragma unroll
        for (int r = 0; r < RB; ++r)
#pragma unroll
            for (int c = 0; c < RB; ++c) Ys[(i0 + r) * ST + j0 + c] = acc[r][c];
        __syncthreads();
    }
    // Q = 2Y - Y*M
    MMUL(Ys, Ms);
#pragma unroll
    for (int r = 0; r < RB; ++r)
#pragma unroll
        for (int c = 0; c < RB; ++c)
            O[(i0 + r) * N + j0 + c] =
                2.f * Ys[(i0 + r) * ST + j0 + c] - acc[r][c];
#undef MMUL
}

__global__ __launch_bounds__(256) void cayley_all(CayleyJobs jobs,
                                                  const int* __restrict__ flag) {
    __shared__ float lds[3 * 80 * 81];  // 77,760 B: Ms | Ys | Ts
    const int isb = *flag;
    const int bid = blockIdx.x;
    int j, start, n;
    if (bid < 16)       { j = 0; start = 0;   n = 80; }
    else if (bid < 96)  { j = 1; start = 16;  n = 16; }
    else if (bid < 112) { j = 2; start = 96;  n = 48; }
    else if (bid < 160) { j = 3; start = 112; n = 16; }
    else if (bid < 176) { j = 4; start = 160; n = 48; }
    else if (bid < 224) { j = 5; start = 176; n = 16; }
    else if (bid < 240) { j = 6; start = 224; n = 80; }
    else                { j = 7; start = 240; n = 16; }
    const int sub = bid - start;
    const size_t esz = isb ? 2 : 4;
    const char* Wb = (const char*)jobs.W[j] + (size_t)sub * n * n * esz;
    float* O = jobs.out[j] + (size_t)sub * n * n;
    float* Ms = lds;
    float* Ys = lds + 80 * 81;
    float* Ts = lds + 2 * 80 * 81;
    if (n == 80)
        cayley_block<80>(Wb, isb, O, Ms, Ys, Ts);
    else if (n == 48)
        cayley_block<48>(Wb, isb, O, Ms, Ys, Ts);
    else
        cayley_block<16>(Wb, isb, O, Ms, Ys, Ts);
}

// ------- fused fold: WeffT[o][k*bdim+b] = esc*sc[o]*sum_c A[k][b][c]*t[c],
//         t[c] = sum_j B[c][k][j]*W[o][j*bdim+c].  One block per o. ---------
template <typename T>
__global__ __launch_bounds__(256) void build_weff2(const T* __restrict__ W,
                                                   const float* __restrict__ Ac,
                                                   const float* __restrict__ Bc,
                                                   const T* __restrict__ scale,
                                                   uint16_t* __restrict__ WeffT,
                                                   int bdim, int Din,
                                                   const int* __restrict__ flag, int want,
                                                   float escale) {
    if (*flag != want) return;
    __shared__ float Wrow[1280];
    __shared__ float tvec[80];
    const int o = blockIdx.x, tid = threadIdx.x;
    for (int i = tid; i < Din; i += 256) Wrow[i] = loadf(W + (size_t)o * Din + i);
    __syncthreads();
    float sc = loadf(scale + o) * escale;
    for (int k = 0; k < 16; ++k) {
        if (tid < bdim) {
            const float* Bm = Bc + tid * 256 + k * 16;  // B[c=tid][k][j]
            float s = 0.f;
#pragma unroll
            for (int j = 0; j < 16; ++j) s += Bm[j] * Wrow[j * bdim + tid];
            tvec[tid] = s;
        }
        __syncthreads();
        if (tid < bdim) {  // tid = beta
            const float* Am = Ac + ((size_t)k * bdim + tid) * bdim;
            float s = 0.f;
            for (int c = 0; c < bdim; ++c) s += Am[c] * tvec[c];
            WeffT[(size_t)o * Din + k * bdim + tid] = f2bf(s * sc);
        }
        __syncthreads();
    }
}

// ---------------- C[M][N] = A[M][K]*Bt[N][K]^T (+bias), bf16 MFMA ----------
#define BM 128
#define BN 128
#define BKK 32
template <typename T>
__global__ __launch_bounds__(256) void gemm_bt(const T* __restrict__ A,
                                               const uint16_t* __restrict__ Bt,
                                               void* __restrict__ Cv,
                                               const void* __restrict__ biasv,
                                               int M, int N, int K,
                                               const int* __restrict__ flag, int want,
                                               int flagio) {
    if (want >= 0 && *flag != want) return;
    const bool io32 = flagio && (*flag == 0);
    __shared__ uint16_t As[BM * BKK];
    __shared__ uint16_t Bs[BN * BKK];
    const int n0 = blockIdx.x * BN, m0 = blockIdx.y * BM;
    const int tid = threadIdx.x;
    const int wave = tid >> 6, lane = tid & 63;
    const int wm = (wave & 1) * 64, wn = (wave >> 1) * 64;
    const int l16 = lane & 15, quad = lane >> 4;

    floatx4 acc[4][4];
#pragma unroll
    for (int i = 0; i < 4; ++i)
#pragma unroll
        for (int j = 0; j < 4; ++j) {
            floatx4 z = {0.f, 0.f, 0.f, 0.f};
            acc[i][j] = z;
        }

    for (int k0 = 0; k0 < K; k0 += BKK) {
        // B staging: 512 x 16B chunks
#pragma unroll
        for (int r = 0; r < 2; ++r) {
            int chunk = tid + r * 256;
            int row = chunk >> 2, c4 = chunk & 3;
            *(uint4*)(&Bs[row * BKK + c4 * 8]) =
                *(const uint4*)(Bt + (size_t)(n0 + row) * K + k0 + c4 * 8);
        }
        // A staging
        if constexpr (sizeof(T) == 2) {
#pragma unroll
            for (int r = 0; r < 2; ++r) {
                int chunk = tid + r * 256;
                int row = chunk >> 2, c4 = chunk & 3;
                int ar = m0 + row;
                ar = ar < M ? ar : M - 1;  // ragged M: clamp load, mask store
                *(uint4*)(&As[row * BKK + c4 * 8]) =
                    *(const uint4*)(A + (size_t)ar * K + k0 + c4 * 8);
            }
        } else {
#pragma unroll
            for (int r = 0; r < 4; ++r) {
                int chunk = tid + r * 256;  // 1024 x float4 chunks
                int row = chunk >> 3, c8 = chunk & 7;
                int ar = m0 + row;
                ar = ar < M ? ar : M - 1;
                float4 v = *(const float4*)(A + (size_t)ar * K + k0 + c8 * 4);
                uint32_t p0 = (uint32_t)f2bf(v.x) | ((uint32_t)f2bf(v.y) << 16);
                uint32_t p1 = (uint32_t)f2bf(v.z) | ((uint32_t)f2bf(v.w) << 16);
                *(uint2*)(&As[row * BKK + c8 * 4]) = make_uint2(p0, p1);
            }
        }
        __syncthreads();
        short8 af[4], bfr[4];
#pragma unroll
        for (int i = 0; i < 4; ++i)
            af[i] = *(const short8*)(&As[(wm + i * 16 + l16) * BKK + quad * 8]);
#pragma unroll
        for (int j = 0; j < 4; ++j)
            bfr[j] = *(const short8*)(&Bs[(wn + j * 16 + l16) * BKK + quad * 8]);
#pragma unroll
        for (int i = 0; i < 4; ++i)
#pragma unroll
            for (int j = 0; j < 4; ++j)
                acc[i][j] = __builtin_amdgcn_mfma_f32_16x16x32_bf16(af[i], bfr[j],
                                                                    acc[i][j], 0, 0, 0);
        __syncthreads();
    }

    // C/D layout: col = lane&15, row = quad*4 + reg  [m89/m91-verified]
#pragma unroll
    for (int i = 0; i < 4; ++i) {
#pragma unroll
        for (int r = 0; r < 4; ++r) {
            int row = m0 + wm + i * 16 + quad * 4 + r;
            if (row < M) {
#pragma unroll
                for (int j = 0; j < 4; ++j) {
                    int col = n0 + wn + j * 16 + l16;
                    float v = acc[i][j][r];
                    if (biasv)
                        v += io32 ? ((const float*)biasv)[col]
                                  : bf2f(((const uint16_t*)biasv)[col]);
                    size_t idx = (size_t)row * N + col;
                    if (io32)
                        ((float*)Cv)[idx] = v;
                    else
                        ((uint16_t*)Cv)[idx] = f2bf(v);
                }
            }
        }
    }
}

// ---------------- MFMA attention: T=77, dh=64 ------------------------------
// Block: 256 thr = 4 waves, one (b,h), 256 q-rows (64/wave, 4 groups of 16).
// Swapped QK^T (scores^T = K.Q^T) -> softmax in 4-lane quad groups ->
// P (normalized, bf16 hi+lo) via per-wave swizzled LDS -> PV MFMA.
// dh^-0.5 is folded into WqT (exact pow2), so no score scaling here.
__global__ __launch_bounds__(256) void attn_mfma(const uint16_t* __restrict__ kbuf,
                                                 const uint16_t* __restrict__ vbuf,
                                                 uint16_t* __restrict__ qbuf) {
    __shared__ uint16_t Ks[80 * 64];      // [t][d], stride 128B, XOR-swz
    __shared__ uint16_t VT[64 * 128];     // [d][t], stride 256B, XOR-swz, t>=77 zero
    __shared__ uint16_t Ph[4][16 * 128];  // per-wave P hi, [s][t] swz
    __shared__ uint16_t Pl[4][16 * 128];  // per-wave P lo
    const int b = blockIdx.z, h = blockIdx.y;
    const int tid = threadIdx.x;
    const int wave = tid >> 6, lane = tid & 63;
    const int l16 = lane & 15, quad = lane >> 4;

    // stage K (rows t<77 from global, else 0), swizzled
    for (int chunk = tid; chunk < 640; chunk += 256) {
        int t = chunk >> 3, c8 = chunk & 7;
        uint4 v = make_uint4(0u, 0u, 0u, 0u);
        if (t < 77)
            v = *(const uint4*)(kbuf + ((size_t)(b * 77 + t)) * 1280 + h * 64 + c8 * 8);
        int byte = (c8 * 16) ^ ((t & 7) << 4);
        *(uint4*)((char*)&Ks[t * 64] + byte) = v;
    }
    // stage V transposed [d][t], t in [0,96), swizzled
    for (int e = tid; e < 96 * 64; e += 256) {
        int t = e >> 6, d = e & 63;
        uint16_t v = 0;
        if (t < 77) v = vbuf[((size_t)(b * 77 + t)) * 1280 + h * 64 + d];
        int byte = (t * 2) ^ ((d & 7) << 4);
        *(uint16_t*)((char*)&VT[d * 128] + byte) = v;
    }
    // zero the P pad band t in [80,96) (never written by groups)
    {
        uint16_t* PhW = Ph[wave];
        uint16_t* PlW = Pl[wave];
#pragma unroll
        for (int r0 = 0; r0 < 4; r0 += 2) {
            int t0 = 80 + quad * 4 + r0;
            int byte = (t0 * 2) ^ ((l16 & 7) << 4);
            *(uint32_t*)((char*)&PhW[l16 * 128] + byte) = 0u;
            *(uint32_t*)((char*)&PlW[l16 * 128] + byte) = 0u;
        }
    }
    __syncthreads();

    const int s_base = blockIdx.x * 256 + wave * 64;
    uint16_t* PhW = Ph[wave];
    uint16_t* PlW = Pl[wave];

    for (int g = 0; g < 4; ++g) {
        const int s0 = s_base + g * 16;
        // Q fragments straight from global (wave-coalesced 64B segments)
        const uint16_t* qrow = qbuf + ((size_t)(b * 4096 + s0 + l16)) * 1280 + h * 64;
        short8 qf0 = *(const short8*)(qrow + quad * 8);
        short8 qf1 = *(const short8*)(qrow + 32 + quad * 8);

        // scores^T[t][s]: acc over 5 t-tiles, k-dim = dh (2 chunks of 32)
        floatx4 sacc[5];
#pragma unroll
        for (int T = 0; T < 5; ++T) {
            floatx4 z = {0.f, 0.f, 0.f, 0.f};
            sacc[T] = z;
        }
#pragma unroll
        for (int T = 0; T < 5; ++T) {
            int trow = T * 16 + l16;
            const char* krow = (const char*)&Ks[trow * 64];
            int swz = (trow & 7) << 4;
            short8 ka0 = *(const short8*)(krow + ((quad * 16) ^ swz));
            short8 ka1 = *(const short8*)(krow + ((64 + quad * 16) ^ swz));
            sacc[T] = __builtin_amdgcn_mfma_f32_16x16x32_bf16(ka0, qf0, sacc[T], 0, 0, 0);
            sacc[T] = __builtin_amdgcn_mfma_f32_16x16x32_bf16(ka1, qf1, sacc[T], 0, 0, 0);
        }

        // softmax: lane holds 20 t-values for q-row s = s0+l16
        float sc[5][4];
        float m = -1e30f;
#pragma unroll
        for (int T = 0; T < 5; ++T)
#pragma unroll
            for (int r = 0; r < 4; ++r) {
                sc[T][r] = sacc[T][r];
                m = fmaxf(m, sc[T][r]);
            }
        m = fmaxf(m, __shfl_xor(m, 16));
        m = fmaxf(m, __shfl_xor(m, 32));
        float den = 0.f;
#pragma unroll
        for (int T = 0; T < 5; ++T)
#pragma unroll
            for (int r = 0; r < 4; ++r) {
                float p = __expf(sc[T][r] - m);
                if (T == 4 && r > 0) p = (quad == 3) ? 0.f : p;  // t>=77 mask
                sc[T][r] = p;
                den += p;
            }
        den += __shfl_xor(den, 16);
        den += __shfl_xor(den, 32);
        float rden = 1.f / den;

        // write normalized P as bf16 hi+lo into per-wave swizzled LDS
#pragma unroll
        for (int T = 0; T < 5; ++T) {
#pragma unroll
            for (int r0 = 0; r0 < 4; r0 += 2) {
                float p0 = sc[T][r0] * rden, p1 = sc[T][r0 + 1] * rden;
                uint16_t h0 = f2bf(p0), h1 = f2bf(p1);
                float l0f = p0 - bf2f(h0), l1f = p1 - bf2f(h1);
                uint16_t lo0 = f2bf(l0f), lo1 = f2bf(l1f);
                int t0 = T * 16 + quad * 4 + r0;
                int byte = (t0 * 2) ^ ((l16 & 7) << 4);
                *(uint32_t*)((char*)&PhW[l16 * 128] + byte) =
                    (uint32_t)h0 | ((uint32_t)h1 << 16);
                *(uint32_t*)((char*)&PlW[l16 * 128] + byte) =
                    (uint32_t)lo0 | ((uint32_t)lo1 << 16);
            }
        }
        // same-wave LDS write->read: in-order LDS pipe + drain
        asm volatile("s_waitcnt lgkmcnt(0)" ::: "memory");

        // PV: out[s][d] = P[s][t] * V[t][d], k-dim t = 96 (3 chunks)
        short8 pa_h[3], pa_l[3];
        {
            const char* prow_h = (const char*)&PhW[l16 * 128];
            const char* prow_l = (const char*)&PlW[l16 * 128];
            int swz = (l16 & 7) << 4;
#pragma unroll
            for (int c = 0; c < 3; ++c) {
                pa_h[c] = *(const short8*)(prow_h + ((c * 64 + quad * 16) ^ swz));
                pa_l[c] = *(const short8*)(prow_l + ((c * 64 + quad * 16) ^ swz));
            }
        }
        floatx4 oacc[4];
#pragma unroll
        for (int dt = 0; dt < 4; ++dt) {
            floatx4 z = {0.f, 0.f, 0.f, 0.f};
            oacc[dt] = z;
        }
#pragma unroll
        for (int dt = 0; dt < 4; ++dt) {
            int drow = dt * 16 + l16;
            const char* vrow = (const char*)&VT[drow * 128];
            int swz = (drow & 7) << 4;
#pragma unroll
            for (int c = 0; c < 3; ++c) {
                short8 vf = *(const short8*)(vrow + ((c * 64 + quad * 16) ^ swz));
                oacc[dt] = __builtin_amdgcn_mfma_f32_16x16x32_bf16(pa_h[c], vf, oacc[dt], 0, 0, 0);
                oacc[dt] = __builtin_amdgcn_mfma_f32_16x16x32_bf16(pa_l[c], vf, oacc[dt], 0, 0, 0);
            }
        }

        // store out in place over q rows: row = s0 + quad*4 + r, col = dt*16+l16
#pragma unroll
        for (int r = 0; r < 4; ++r) {
            int s = s0 + quad * 4 + r;
            uint16_t* orow = qbuf + ((size_t)(b * 4096 + s)) * 1280 + h * 64;
#pragma unroll
            for (int dt = 0; dt < 4; ++dt) orow[dt * 16 + l16] = f2bf(oacc[dt][r]);
        }
    }
}

// ---------------------------------------------------------------------------
extern "C" void kernel_launch(void* const* d_in, const int* in_sizes, int n_in,
                              void* d_out, int out_size, void* d_ws, size_t ws_size,
                              hipStream_t stream) {
    (void)in_sizes; (void)n_in; (void)out_size; (void)ws_size;

    // workspace layout (256B-aligned), total ~94.7 MB
    char* ws = (char*)d_ws;
    int* flag      = (int*)(ws + 0);
    float* AcQ     = (float*)(ws + 409856);
    float* AcK     = (float*)(ws + 819456);
    float* AcV     = (float*)(ws + 966912);
    float* AcO     = (float*)(ws + 1114368);
    float* BcQ     = (float*)(ws + 1523968);
    float* BcK     = (float*)(ws + 1605888);
    float* BcV     = (float*)(ws + 1655040);
    float* BcO     = (float*)(ws + 1704192);
    uint16_t* WqT  = (uint16_t*)(ws + 1786112);   // [1280][1280]
    uint16_t* WkT  = (uint16_t*)(ws + 5062912);   // [1280][768]
    uint16_t* WvT  = (uint16_t*)(ws + 7028992);
    uint16_t* WoT  = (uint16_t*)(ws + 8995072);   // [1280][1280]
    uint16_t* kb   = (uint16_t*)(ws + 12271872);  // [616][1280]
    uint16_t* vb   = (uint16_t*)(ws + 13848832);
    uint16_t* qb   = (uint16_t*)(ws + 15425792);  // [32768][1280]

    detect_dtype<<<1, 64, 0, stream>>>((const uint16_t*)d_in[0], flag);

    // Cayley (Newton-Schulz): all 8 matrices, both dtypes, ONE launch.
    CayleyJobs cj;
    cj.W[0] = d_in[2]; cj.out[0] = AcQ;
    cj.W[1] = d_in[3]; cj.out[1] = BcQ;
    cj.W[2] = d_in[4]; cj.out[2] = AcK;
    cj.W[3] = d_in[5]; cj.out[3] = BcK;
    cj.W[4] = d_in[6]; cj.out[4] = AcV;
    cj.W[5] = d_in[7]; cj.out[5] = BcV;
    cj.W[6] = d_in[8]; cj.out[6] = AcO;
    cj.W[7] = d_in[9]; cj.out[7] = BcO;
    cayley_all<<<320, 256, 0, stream>>>(cj, flag);

    // Fold Monarch + W^T + scale -> WeffT (bf16), dual-launched.
    // Q gets an extra 0.125 = dh^-0.5 (exact pow2) so attention needs no scale.
#define WEFF(widx, Ac, Bc, sidx, dst, bdim, Din, esc)                             \
    build_weff2<uint16_t><<<1280, 256, 0, stream>>>((const uint16_t*)d_in[widx], Ac, Bc, \
        (const uint16_t*)d_in[sidx], dst, bdim, Din, flag, 1, esc);               \
    build_weff2<float><<<1280, 256, 0, stream>>>((const float*)d_in[widx], Ac, Bc,       \
        (const float*)d_in[sidx], dst, bdim, Din, flag, 0, esc)
    WEFF(10, AcQ, BcQ, 15, WqT, 80, 1280, 0.125f);
    WEFF(11, AcK, BcK, 16, WkT, 48, 768, 1.0f);
    WEFF(12, AcV, BcV, 17, WvT, 48, 768, 1.0f);
    WEFF(13, AcO, BcO, 18, WoT, 80, 1280, 1.0f);
#undef WEFF

    // Projections (C always bf16 internal)
    gemm_bt<uint16_t><<<dim3(10, 256), 256, 0, stream>>>((const uint16_t*)d_in[0], WqT, qb,
                                                         nullptr, 32768, 1280, 1280, flag, 1, 0);
    gemm_bt<float><<<dim3(10, 256), 256, 0, stream>>>((const float*)d_in[0], WqT, qb,
                                                      nullptr, 32768, 1280, 1280, flag, 0, 0);
    gemm_bt<uint16_t><<<dim3(10, 5), 256, 0, stream>>>((const uint16_t*)d_in[1], WkT, kb,
                                                       nullptr, 616, 1280, 768, flag, 1, 0);
    gemm_bt<float><<<dim3(10, 5), 256, 0, stream>>>((const float*)d_in[1], WkT, kb,
                                                    nullptr, 616, 1280, 768, flag, 0, 0);
    gemm_bt<uint16_t><<<dim3(10, 5), 256, 0, stream>>>((const uint16_t*)d_in[1], WvT, vb,
                                                       nullptr, 616, 1280, 768, flag, 1, 0);
    gemm_bt<float><<<dim3(10, 5), 256, 0, stream>>>((const float*)d_in[1], WvT, vb,
                                                    nullptr, 616, 1280, 768, flag, 0, 0);

    // Attention (in-place on qb, always bf16), MFMA path
    attn_mfma<<<dim3(16, 20, 8), 256, 0, stream>>>(kb, vb, qb);

    // Output projection + bias -> d_out, out dtype follows flag
    gemm_bt<uint16_t><<<dim3(10, 256), 256, 0, stream>>>(qb, WoT, d_out, d_in[14],
                                                         32768, 1280, 1280, flag, -1, 1);
}

// Round 3
// 1073.587 us; speedup vs baseline: 5.1002x; 1.0315x over previous
//
#include <hip/hip_runtime.h>
#include <stdint.h>

// ---------------- bf16 helpers -------------------------------------------
__device__ __forceinline__ float bf2f(uint16_t u) {
    uint32_t x = ((uint32_t)u) << 16;
    float f;
    __builtin_memcpy(&f, &x, 4);
    return f;
}
__device__ __forceinline__ uint16_t f2bf(float f) {
    uint32_t u;
    __builtin_memcpy(&u, &f, 4);
    uint32_t r = (u + 0x7fffu + ((u >> 16) & 1u)) >> 16;  // RNE
    return (uint16_t)r;
}
__device__ __forceinline__ float loadf(const float* p) { return *p; }
__device__ __forceinline__ float loadf(const uint16_t* p) { return bf2f(*p); }

typedef __attribute__((ext_vector_type(8))) short short8;   // 8 bf16 (MFMA A/B)
typedef __attribute__((ext_vector_type(4))) float floatx4;  // MFMA C/D

// async global->LDS, 16B per lane; LDS dest = wave-uniform base + lane*16
__device__ __forceinline__ void gload_lds16(const void* g, void* l) {
    __builtin_amdgcn_global_load_lds(
        (const __attribute__((address_space(1))) uint32_t*)g,
        (__attribute__((address_space(3))) uint32_t*)l, 16, 0, 0);
}

// ---------------- dtype detector ------------------------------------------
__global__ void detect_dtype(const uint16_t* __restrict__ x, int* __restrict__ flag) {
    int lane = threadIdx.x;  // 64 threads
    int cnt = 0;
    for (int i = 0; i < 8; ++i) {
        uint16_t u = x[lane * 8 + i];
        int e = (u >> 7) & 0xff;
        if (u == 0 || (e >= 96 && e <= 159)) ++cnt;
    }
    for (int off = 32; off; off >>= 1) cnt += __shfl_down(cnt, off);
    if (lane == 0) *flag = (cnt >= 448) ? 1 : 0;  // 1 = bf16 inputs, 0 = f32
}

// ---------------- Cayley via Newton-Schulz, all 8 matrices in ONE launch ---
struct CayleyJobs {
    const void* W[8];
    float* out[8];
};

template <int N>
__device__ __forceinline__ void cayley_block(const char* __restrict__ Wb, int isb,
                                             float* __restrict__ O,
                                             float* __restrict__ Ms,
                                             float* __restrict__ Ys,
                                             float* __restrict__ Ts) {
    constexpr int ST = N + 1;   // pad leading dim
    constexpr int RB = N / 16;  // 80->5, 48->3, 16->1
    const int tid = threadIdx.x;
    // stage: Ms = I+S, Ys = I-S  (S = W - W^T)
    for (int e = tid; e < N * N; e += 256) {
        int i = e / N, j = e - i * N;
        float wij, wji;
        if (isb) {
            wij = bf2f(((const uint16_t*)Wb)[i * N + j]);
            wji = bf2f(((const uint16_t*)Wb)[j * N + i]);
        } else {
            wij = ((const float*)Wb)[i * N + j];
            wji = ((const float*)Wb)[j * N + i];
        }
        float s = wij - wji;
        float idt = (i == j) ? 1.f : 0.f;
        Ms[i * ST + j] = idt + s;
        Ys[i * ST + j] = idt - s;
    }
    __syncthreads();
    const int i0 = (tid >> 4) * RB, j0 = (tid & 15) * RB;
    float acc[RB][RB];

#define MMUL(Amat, Bmat)                                                          \
    _Pragma("unroll") for (int r = 0; r < RB; ++r)                                \
        _Pragma("unroll") for (int c = 0; c < RB; ++c) acc[r][c] = 0.f;           \
    _Pragma("unroll 4") for (int k = 0; k < N; ++k) {                             \
        float a_[RB], b_[RB];                                                     \
        _Pragma("unroll") for (int r = 0; r < RB; ++r)                            \
            a_[r] = Amat[(i0 + r) * ST + k];                                      \
        _Pragma("unroll") for (int c = 0; c < RB; ++c)                            \
            b_[c] = Bmat[k * ST + j0 + c];                                        \
        _Pragma("unroll") for (int r = 0; r < RB; ++r)                            \
            _Pragma("unroll") for (int c = 0; c < RB; ++c)                        \
                acc[r][c] = fmaf(a_[r], b_[c], acc[r][c]);                        \
    }

    for (int it = 0; it < 5; ++it) {
        // Ts = 2I - Ms*Ys
        MMUL(Ms, Ys);
#pragma unroll
        for (int r = 0; r < RB; ++r)
#pragma unroll
            for (int c = 0; c < RB; ++c)
                Ts[(i0 + r) * ST + j0 + c] =
                    ((i0 + r) == (j0 + c) ? 2.f : 0.f) - acc[r][c];
        __syncthreads();
        // Ynew = Ys*Ts (in regs), write back after all reads complete
        MMUL(Ys, Ts);
        __syncthreads();
#pragma unroll
        for (int r = 0; r < RB; ++r)
#pragma unroll
            for (int c = 0; c < RB; ++c) Ys[(i0 + r) * ST + j0 + c] = acc[r][c];
        __syncthreads();
    }
    // Q = 2Y - Y*M
    MMUL(Ys, Ms);
#pragma unroll
    for (int r = 0; r < RB; ++r)
#pragma unroll
        for (int c = 0; c < RB; ++c)
            O[(i0 + r) * N + j0 + c] =
                2.f * Ys[(i0 + r) * ST + j0 + c] - acc[r][c];
#undef MMUL
}

__global__ __launch_bounds__(256) void cayley_all(CayleyJobs jobs,
                                                  const int* __restrict__ flag) {
    __shared__ float lds[3 * 80 * 81];  // 77,760 B: Ms | Ys | Ts
    const int isb = *flag;
    const int bid = blockIdx.x;
    int j, start, n;
    if (bid < 16)       { j = 0; start = 0;   n = 80; }
    else if (bid < 96)  { j = 1; start = 16;  n = 16; }
    else if (bid < 112) { j = 2; start = 96;  n = 48; }
    else if (bid < 160) { j = 3; start = 112; n = 16; }
    else if (bid < 176) { j = 4; start = 160; n = 48; }
    else if (bid < 224) { j = 5; start = 176; n = 16; }
    else if (bid < 240) { j = 6; start = 224; n = 80; }
    else                { j = 7; start = 240; n = 16; }
    const int sub = bid - start;
    const size_t esz = isb ? 2 : 4;
    const char* Wb = (const char*)jobs.W[j] + (size_t)sub * n * n * esz;
    float* O = jobs.out[j] + (size_t)sub * n * n;
    float* Ms = lds;
    float* Ys = lds + 80 * 81;
    float* Ts = lds + 2 * 80 * 81;
    if (n == 80)
        cayley_block<80>(Wb, isb, O, Ms, Ys, Ts);
    else if (n == 48)
        cayley_block<48>(Wb, isb, O, Ms, Ys, Ts);
    else
        cayley_block<16>(Wb, isb, O, Ms, Ys, Ts);
}

// ------- fused fold: WeffT[o][k*bdim+b] = esc*sc[o]*sum_c A[k][b][c]*t[c],
//         t[c] = sum_j B[c][k][j]*W[o][j*bdim+c].  One block per o. ---------
template <typename T>
__global__ __launch_bounds__(256) void build_weff2(const T* __restrict__ W,
                                                   const float* __restrict__ Ac,
                                                   const float* __restrict__ Bc,
                                                   const T* __restrict__ scale,
                                                   uint16_t* __restrict__ WeffT,
                                                   int bdim, int Din,
                                                   const int* __restrict__ flag, int want,
                                                   float escale) {
    if (*flag != want) return;
    __shared__ float Wrow[1280];
    __shared__ float tvec[80];
    const int o = blockIdx.x, tid = threadIdx.x;
    for (int i = tid; i < Din; i += 256) Wrow[i] = loadf(W + (size_t)o * Din + i);
    __syncthreads();
    float sc = loadf(scale + o) * escale;
    for (int k = 0; k < 16; ++k) {
        if (tid < bdim) {
            const float* Bm = Bc + tid * 256 + k * 16;  // B[c=tid][k][j]
            float s = 0.f;
#pragma unroll
            for (int j = 0; j < 16; ++j) s += Bm[j] * Wrow[j * bdim + tid];
            tvec[tid] = s;
        }
        __syncthreads();
        if (tid < bdim) {  // tid = beta
            const float* Am = Ac + ((size_t)k * bdim + tid) * bdim;
            float s = 0.f;
            for (int c = 0; c < bdim; ++c) s += Am[c] * tvec[c];
            WeffT[(size_t)o * Din + k * bdim + tid] = f2bf(s * sc);
        }
        __syncthreads();
    }
}

// ---------------- C[M][N] = A[M][K]*Bt[N][K]^T (+bias), bf16 MFMA ----------
// XCD-aware bijective workgroup swizzle (T1, m204): consecutive remapped ids
// (same A strip) stay on one XCD's L2. bf16 path stages via global_load_lds
// width=16 (T-ladder step 3); f32 path reg-stages with convert.
#define BM 128
#define BN 128
#define BKK 32
template <typename T>
__global__ __launch_bounds__(256) void gemm_bt(const T* __restrict__ A,
                                               const uint16_t* __restrict__ Bt,
                                               void* __restrict__ Cv,
                                               const void* __restrict__ biasv,
                                               int M, int N, int K,
                                               const int* __restrict__ flag, int want,
                                               int flagio) {
    if (want >= 0 && *flag != want) return;
    const bool io32 = flagio && (*flag == 0);
    __shared__ uint16_t As[BM * BKK];
    __shared__ uint16_t Bs[BN * BKK];
    // T1: bijective XCD swizzle of the flat workgroup id
    const int nwg = gridDim.x * gridDim.y;
    const int orig = blockIdx.y * gridDim.x + blockIdx.x;
    const int qc = nwg >> 3, rc = nwg & 7;
    const int xcd = orig & 7, sub = orig >> 3;
    const int wg = (xcd < rc ? xcd * (qc + 1) : rc * (qc + 1) + (xcd - rc) * qc) + sub;
    const int n0 = (wg % gridDim.x) * BN, m0 = (wg / gridDim.x) * BM;
    const int tid = threadIdx.x;
    const int wave = tid >> 6, lane = tid & 63;
    const int wm = (wave & 1) * 64, wn = (wave >> 1) * 64;
    const int l16 = lane & 15, quad = lane >> 4;

    floatx4 acc[4][4];
#pragma unroll
    for (int i = 0; i < 4; ++i)
#pragma unroll
        for (int j = 0; j < 4; ++j) {
            floatx4 z = {0.f, 0.f, 0.f, 0.f};
            acc[i][j] = z;
        }

    for (int k0 = 0; k0 < K; k0 += BKK) {
        if constexpr (sizeof(T) == 2) {
            // async staging: per wave 2 chunks of 16 rows for A and B each.
            // LDS dest = chunk*1024 + lane*16  == linear [row][32] layout.
#pragma unroll
            for (int i = 0; i < 2; ++i) {
                int chunk = wave * 2 + i;
                int row = chunk * 16 + (lane >> 2);
                int c8 = (lane & 3) * 8;
                int ar = m0 + row;
                ar = ar < M ? ar : M - 1;  // ragged M: clamp source
                gload_lds16(A + (size_t)ar * K + k0 + c8, (char*)As + chunk * 1024);
                gload_lds16(Bt + (size_t)(n0 + row) * K + k0 + c8,
                            (char*)Bs + chunk * 1024);
            }
        } else {
            // B staging: 512 x 16B chunks
#pragma unroll
            for (int r = 0; r < 2; ++r) {
                int chunk = tid + r * 256;
                int row = chunk >> 2, c4 = chunk & 3;
                *(uint4*)(&Bs[row * BKK + c4 * 8]) =
                    *(const uint4*)(Bt + (size_t)(n0 + row) * K + k0 + c4 * 8);
            }
            // A staging with f32->bf16 convert
#pragma unroll
            for (int r = 0; r < 4; ++r) {
                int chunk = tid + r * 256;  // 1024 x float4 chunks
                int row = chunk >> 3, c8 = chunk & 7;
                int ar = m0 + row;
                ar = ar < M ? ar : M - 1;
                float4 v = *(const float4*)(A + (size_t)ar * K + k0 + c8 * 4);
                uint32_t p0 = (uint32_t)f2bf(v.x) | ((uint32_t)f2bf(v.y) << 16);
                uint32_t p1 = (uint32_t)f2bf(v.z) | ((uint32_t)f2bf(v.w) << 16);
                *(uint2*)(&As[row * BKK + c8 * 4]) = make_uint2(p0, p1);
            }
        }
        __syncthreads();
        short8 af[4], bfr[4];
#pragma unroll
        for (int i = 0; i < 4; ++i)
            af[i] = *(const short8*)(&As[(wm + i * 16 + l16) * BKK + quad * 8]);
#pragma unroll
        for (int j = 0; j < 4; ++j)
            bfr[j] = *(const short8*)(&Bs[(wn + j * 16 + l16) * BKK + quad * 8]);
#pragma unroll
        for (int i = 0; i < 4; ++i)
#pragma unroll
            for (int j = 0; j < 4; ++j)
                acc[i][j] = __builtin_amdgcn_mfma_f32_16x16x32_bf16(af[i], bfr[j],
                                                                    acc[i][j], 0, 0, 0);
        __syncthreads();
    }

    // C/D layout: col = lane&15, row = quad*4 + reg  [m89/m91-verified]
#pragma unroll
    for (int i = 0; i < 4; ++i) {
#pragma unroll
        for (int r = 0; r < 4; ++r) {
            int row = m0 + wm + i * 16 + quad * 4 + r;
            if (row < M) {
#pragma unroll
                for (int j = 0; j < 4; ++j) {
                    int col = n0 + wn + j * 16 + l16;
                    float v = acc[i][j][r];
                    if (biasv)
                        v += io32 ? ((const float*)biasv)[col]
                                  : bf2f(((const uint16_t*)biasv)[col]);
                    size_t idx = (size_t)row * N + col;
                    if (io32)
                        ((float*)Cv)[idx] = v;
                    else
                        ((uint16_t*)Cv)[idx] = f2bf(v);
                }
            }
        }
    }
}

// ---------------- MFMA attention: T=77, dh=64 ------------------------------
// Block: 256 thr = 4 waves, one (b,h), 256 q-rows (64/wave, 4 groups of 16).
// Swapped QK^T (scores^T = K.Q^T) -> softmax in 4-lane quad groups ->
// P (normalized, bf16 hi+lo) via per-wave swizzled LDS -> PV MFMA.
// dh^-0.5 is folded into WqT (exact pow2), so no score scaling here.
__global__ __launch_bounds__(256) void attn_mfma(const uint16_t* __restrict__ kbuf,
                                                 const uint16_t* __restrict__ vbuf,
                                                 uint16_t* __restrict__ qbuf) {
    __shared__ uint16_t Ks[80 * 64];      // [t][d], stride 128B, XOR-swz
    __shared__ uint16_t VT[64 * 128];     // [d][t], stride 256B, XOR-swz, t>=77 zero
    __shared__ uint16_t Ph[4][16 * 128];  // per-wave P hi, [s][t] swz
    __shared__ uint16_t Pl[4][16 * 128];  // per-wave P lo
    const int b = blockIdx.z, h = blockIdx.y;
    const int tid = threadIdx.x;
    const int wave = tid >> 6, lane = tid & 63;
    const int l16 = lane & 15, quad = lane >> 4;

    // stage K (rows t<77 from global, else 0), swizzled
    for (int chunk = tid; chunk < 640; chunk += 256) {
        int t = chunk >> 3, c8 = chunk & 7;
        uint4 v = make_uint4(0u, 0u, 0u, 0u);
        if (t < 77)
            v = *(const uint4*)(kbuf + ((size_t)(b * 77 + t)) * 1280 + h * 64 + c8 * 8);
        int byte = (c8 * 16) ^ ((t & 7) << 4);
        *(uint4*)((char*)&Ks[t * 64] + byte) = v;
    }
    // stage V transposed [d][t], t in [0,96), swizzled
    for (int e = tid; e < 96 * 64; e += 256) {
        int t = e >> 6, d = e & 63;
        uint16_t v = 0;
        if (t < 77) v = vbuf[((size_t)(b * 77 + t)) * 1280 + h * 64 + d];
        int byte = (t * 2) ^ ((d & 7) << 4);
        *(uint16_t*)((char*)&VT[d * 128] + byte) = v;
    }
    // zero the P pad band t in [80,96) (never written by groups)
    {
        uint16_t* PhW = Ph[wave];
        uint16_t* PlW = Pl[wave];
#pragma unroll
        for (int r0 = 0; r0 < 4; r0 += 2) {
            int t0 = 80 + quad * 4 + r0;
            int byte = (t0 * 2) ^ ((l16 & 7) << 4);
            *(uint32_t*)((char*)&PhW[l16 * 128] + byte) = 0u;
            *(uint32_t*)((char*)&PlW[l16 * 128] + byte) = 0u;
        }
    }
    __syncthreads();

    const int s_base = blockIdx.x * 256 + wave * 64;
    uint16_t* PhW = Ph[wave];
    uint16_t* PlW = Pl[wave];

    for (int g = 0; g < 4; ++g) {
        const int s0 = s_base + g * 16;
        // Q fragments straight from global (wave-coalesced 64B segments)
        const uint16_t* qrow = qbuf + ((size_t)(b * 4096 + s0 + l16)) * 1280 + h * 64;
        short8 qf0 = *(const short8*)(qrow + quad * 8);
        short8 qf1 = *(const short8*)(qrow + 32 + quad * 8);

        // scores^T[t][s]: acc over 5 t-tiles, k-dim = dh (2 chunks of 32)
        floatx4 sacc[5];
#pragma unroll
        for (int T = 0; T < 5; ++T) {
            floatx4 z = {0.f, 0.f, 0.f, 0.f};
            sacc[T] = z;
        }
#pragma unroll
        for (int T = 0; T < 5; ++T) {
            int trow = T * 16 + l16;
            const char* krow = (const char*)&Ks[trow * 64];
            int swz = (trow & 7) << 4;
            short8 ka0 = *(const short8*)(krow + ((quad * 16) ^ swz));
            short8 ka1 = *(const short8*)(krow + ((64 + quad * 16) ^ swz));
            sacc[T] = __builtin_amdgcn_mfma_f32_16x16x32_bf16(ka0, qf0, sacc[T], 0, 0, 0);
            sacc[T] = __builtin_amdgcn_mfma_f32_16x16x32_bf16(ka1, qf1, sacc[T], 0, 0, 0);
        }

        // softmax: lane holds 20 t-values for q-row s = s0+l16
        float sc[5][4];
        float m = -1e30f;
#pragma unroll
        for (int T = 0; T < 5; ++T)
#pragma unroll
            for (int r = 0; r < 4; ++r) {
                sc[T][r] = sacc[T][r];
                m = fmaxf(m, sc[T][r]);
            }
        m = fmaxf(m, __shfl_xor(m, 16));
        m = fmaxf(m, __shfl_xor(m, 32));
        float den = 0.f;
#pragma unroll
        for (int T = 0; T < 5; ++T)
#pragma unroll
            for (int r = 0; r < 4; ++r) {
                float p = __expf(sc[T][r] - m);
                if (T == 4 && r > 0) p = (quad == 3) ? 0.f : p;  // t>=77 mask
                sc[T][r] = p;
                den += p;
            }
        den += __shfl_xor(den, 16);
        den += __shfl_xor(den, 32);
        float rden = 1.f / den;

        // write normalized P as bf16 hi+lo into per-wave swizzled LDS
#pragma unroll
        for (int T = 0; T < 5; ++T) {
#pragma unroll
            for (int r0 = 0; r0 < 4; r0 += 2) {
                float p0 = sc[T][r0] * rden, p1 = sc[T][r0 + 1] * rden;
                uint16_t h0 = f2bf(p0), h1 = f2bf(p1);
                float l0f = p0 - bf2f(h0), l1f = p1 - bf2f(h1);
                uint16_t lo0 = f2bf(l0f), lo1 = f2bf(l1f);
                int t0 = T * 16 + quad * 4 + r0;
                int byte = (t0 * 2) ^ ((l16 & 7) << 4);
                *(uint32_t*)((char*)&PhW[l16 * 128] + byte) =
                    (uint32_t)h0 | ((uint32_t)h1 << 16);
                *(uint32_t*)((char*)&PlW[l16 * 128] + byte) =
                    (uint32_t)lo0 | ((uint32_t)lo1 << 16);
            }
        }
        // same-wave LDS write->read: in-order LDS pipe + drain
        asm volatile("s_waitcnt lgkmcnt(0)" ::: "memory");

        // PV: out[s][d] = P[s][t] * V[t][d], k-dim t = 96 (3 chunks)
        short8 pa_h[3], pa_l[3];
        {
            const char* prow_h = (const char*)&PhW[l16 * 128];
            const char* prow_l = (const char*)&PlW[l16 * 128];
            int swz = (l16 & 7) << 4;
#pragma unroll
            for (int c = 0; c < 3; ++c) {
                pa_h[c] = *(const short8*)(prow_h + ((c * 64 + quad * 16) ^ swz));
                pa_l[c] = *(const short8*)(prow_l + ((c * 64 + quad * 16) ^ swz));
            }
        }
        floatx4 oacc[4];
#pragma unroll
        for (int dt = 0; dt < 4; ++dt) {
            floatx4 z = {0.f, 0.f, 0.f, 0.f};
            oacc[dt] = z;
        }
#pragma unroll
        for (int dt = 0; dt < 4; ++dt) {
            int drow = dt * 16 + l16;
            const char* vrow = (const char*)&VT[drow * 128];
            int swz = (drow & 7) << 4;
#pragma unroll
            for (int c = 0; c < 3; ++c) {
                short8 vf = *(const short8*)(vrow + ((c * 64 + quad * 16) ^ swz));
                oacc[dt] = __builtin_amdgcn_mfma_f32_16x16x32_bf16(pa_h[c], vf, oacc[dt], 0, 0, 0);
                oacc[dt] = __builtin_amdgcn_mfma_f32_16x16x32_bf16(pa_l[c], vf, oacc[dt], 0, 0, 0);
            }
        }

        // store out in place over q rows: row = s0 + quad*4 + r, col = dt*16+l16
#pragma unroll
        for (int r = 0; r < 4; ++r) {
            int s = s0 + quad * 4 + r;
            uint16_t* orow = qbuf + ((size_t)(b * 4096 + s)) * 1280 + h * 64;
#pragma unroll
            for (int dt = 0; dt < 4; ++dt) orow[dt * 16 + l16] = f2bf(oacc[dt][r]);
        }
    }
}

// ---------------------------------------------------------------------------
extern "C" void kernel_launch(void* const* d_in, const int* in_sizes, int n_in,
                              void* d_out, int out_size, void* d_ws, size_t ws_size,
                              hipStream_t stream) {
    (void)in_sizes; (void)n_in; (void)out_size; (void)ws_size;

    // workspace layout (256B-aligned), total ~94.7 MB
    char* ws = (char*)d_ws;
    int* flag      = (int*)(ws + 0);
    float* AcQ     = (float*)(ws + 409856);
    float* AcK     = (float*)(ws + 819456);
    float* AcV     = (float*)(ws + 966912);
    float* AcO     = (float*)(ws + 1114368);
    float* BcQ     = (float*)(ws + 1523968);
    float* BcK     = (float*)(ws + 1605888);
    float* BcV     = (float*)(ws + 1655040);
    float* BcO     = (float*)(ws + 1704192);
    uint16_t* WqT  = (uint16_t*)(ws + 1786112);   // [1280][1280]
    uint16_t* WkT  = (uint16_t*)(ws + 5062912);   // [1280][768]
    uint16_t* WvT  = (uint16_t*)(ws + 7028992);
    uint16_t* WoT  = (uint16_t*)(ws + 8995072);   // [1280][1280]
    uint16_t* kb   = (uint16_t*)(ws + 12271872);  // [616][1280]
    uint16_t* vb   = (uint16_t*)(ws + 13848832);
    uint16_t* qb   = (uint16_t*)(ws + 15425792);  // [32768][1280]

    detect_dtype<<<1, 64, 0, stream>>>((const uint16_t*)d_in[0], flag);

    // Cayley (Newton-Schulz): all 8 matrices, both dtypes, ONE launch.
    CayleyJobs cj;
    cj.W[0] = d_in[2]; cj.out[0] = AcQ;
    cj.W[1] = d_in[3]; cj.out[1] = BcQ;
    cj.W[2] = d_in[4]; cj.out[2] = AcK;
    cj.W[3] = d_in[5]; cj.out[3] = BcK;
    cj.W[4] = d_in[6]; cj.out[4] = AcV;
    cj.W[5] = d_in[7]; cj.out[5] = BcV;
    cj.W[6] = d_in[8]; cj.out[6] = AcO;
    cj.W[7] = d_in[9]; cj.out[7] = BcO;
    cayley_all<<<320, 256, 0, stream>>>(cj, flag);

    // Fold Monarch + W^T + scale -> WeffT (bf16), dual-launched.
    // Q gets an extra 0.125 = dh^-0.5 (exact pow2) so attention needs no scale.
#define WEFF(widx, Ac, Bc, sidx, dst, bdim, Din, esc)                             \
    build_weff2<uint16_t><<<1280, 256, 0, stream>>>((const uint16_t*)d_in[widx], Ac, Bc, \
        (const uint16_t*)d_in[sidx], dst, bdim, Din, flag, 1, esc);               \
    build_weff2<float><<<1280, 256, 0, stream>>>((const float*)d_in[widx], Ac, Bc,       \
        (const float*)d_in[sidx], dst, bdim, Din, flag, 0, esc)
    WEFF(10, AcQ, BcQ, 15, WqT, 80, 1280, 0.125f);
    WEFF(11, AcK, BcK, 16, WkT, 48, 768, 1.0f);
    WEFF(12, AcV, BcV, 17, WvT, 48, 768, 1.0f);
    WEFF(13, AcO, BcO, 18, WoT, 80, 1280, 1.0f);
#undef WEFF

    // Projections (C always bf16 internal)
    gemm_bt<uint16_t><<<dim3(10, 256), 256, 0, stream>>>((const uint16_t*)d_in[0], WqT, qb,
                                                         nullptr, 32768, 1280, 1280, flag, 1, 0);
    gemm_bt<float><<<dim3(10, 256), 256, 0, stream>>>((const float*)d_in[0], WqT, qb,
                                                      nullptr, 32768, 1280, 1280, flag, 0, 0);
    gemm_bt<uint16_t><<<dim3(10, 5), 256, 0, stream>>>((const uint16_t*)d_in[1], WkT, kb,
                                                       nullptr, 616, 1280, 768, flag, 1, 0);
    gemm_bt<float><<<dim3(10, 5), 256, 0, stream>>>((const float*)d_in[1], WkT, kb,
                                                    nullptr, 616, 1280, 768, flag, 0, 0);
    gemm_bt<uint16_t><<<dim3(10, 5), 256, 0, stream>>>((const uint16_t*)d_in[1], WvT, vb,
                                                       nullptr, 616, 1280, 768, flag, 1, 0);
    gemm_bt<float><<<dim3(10, 5), 256, 0, stream>>>((const float*)d_in[1], WvT, vb,
                                                    nullptr, 616, 1280, 768, flag, 0, 0);

    // Attention (in-place on qb, always bf16), MFMA path
    attn_mfma<<<dim3(16, 20, 8), 256, 0, stream>>>(kb, vb, qb);

    // Output projection + bias -> d_out, out dtype follows flag
    gemm_bt<uint16_t><<<dim3(10, 256), 256, 0, stream>>>(qb, WoT, d_out, d_in[14],
                                                         32768, 1280, 1280, flag, -1, 1);
}